// Round 4
// baseline (187.801 us; speedup 1.0000x reference)
//
#include <hip/hip_runtime.h>
#include <hip/hip_bf16.h>

typedef __bf16 bf16;
typedef bf16 bf16x8 __attribute__((ext_vector_type(8)));
typedef bf16 bf16x4 __attribute__((ext_vector_type(4)));
typedef float f32x4 __attribute__((ext_vector_type(4)));

constexpr int B = 4, C = 512, L = 2048, H = 8, DH = 64;
constexpr int BL = B * L;        // 8192
constexpr int BH = B * H;        // 32
constexpr int N_QKV = 3 * C;     // 1536
constexpr float QSCALE = 0.125f * 1.44269504088896f;  // DH^-0.5 * log2(e), folded into Q
constexpr float EPS = 1e-5f;

// ---- workspace layout (bytes) ----
constexpr size_t SZ = (size_t)BL * C;                 // 4,194,304 elems
constexpr size_t OFF_HN    = 0;                       // SZ bf16
constexpr size_t OFF_WQKV  = OFF_HN    + SZ * 2;      // N_QKV*C bf16
constexpr size_t OFF_WPROJ = OFF_WQKV  + (size_t)N_QKV * C * 2;
constexpr size_t OFF_Q     = OFF_WPROJ + (size_t)C * C * 2;
constexpr size_t OFF_K     = OFF_Q     + SZ * 2;
constexpr size_t OFF_V     = OFF_K     + SZ * 2;      // V stored TRANSPOSED [B,H,DH,L]
constexpr size_t OFF_O     = OFF_V     + SZ * 2;      // (unused)
constexpr size_t OFF_STATS = OFF_O     + SZ * 2;      // (unused)
constexpr size_t OFF_OPART = OFF_STATS + (size_t)BL * 2 * 4;   // [2][BH][L][DH] bf16
constexpr size_t OFF_ML    = OFF_OPART + (size_t)2 * BH * L * DH * 2;  // [2][BH][L] float

__device__ __forceinline__ bf16x8 ld8(const bf16* p) {
  return *(const bf16x8*)p;
}

__device__ __forceinline__ void gll16(const bf16* g, bf16* l) {
  __builtin_amdgcn_global_load_lds(
      (const __attribute__((address_space(1))) unsigned int*)(const void*)g,
      (__attribute__((address_space(3))) unsigned int*)(void*)l, 16, 0, 0);
}

// bias-rounded bf16 pack: (hi16(a+0x8000) low | hi16(b+0x8000) high)
__device__ __forceinline__ unsigned pack_bf16(float a, float b) {
  unsigned ua = __builtin_bit_cast(unsigned, a) + 0x8000u;
  unsigned ub = __builtin_bit_cast(unsigned, b) + 0x8000u;
  return __builtin_amdgcn_perm(ub, ua, 0x07060302u);
}
__device__ __forceinline__ float bf_lo(unsigned u) { return __builtin_bit_cast(float, u << 16); }
__device__ __forceinline__ float bf_hi(unsigned u) { return __builtin_bit_cast(float, u & 0xFFFF0000u); }

// ---------------- fused LayerNorm + weight conversion ----------------
// grid: B * (L/32) = 256 blocks, 1024 threads. x tile (512 c x 32 l fp32) in LDS.
// Tail: converts wqkv (3 strided passes) + wproj (1 pass) to bf16 — replaces k_convert_w.
__global__ __launch_bounds__(1024) void k_ln(const float* __restrict__ x,
                                             const float* __restrict__ gamma,
                                             const float* __restrict__ beta,
                                             const float* __restrict__ wqkv,
                                             const float* __restrict__ wproj,
                                             bf16* __restrict__ hn,
                                             bf16* __restrict__ wqkv_b,
                                             bf16* __restrict__ wproj_b) {
  int blk = blockIdx.x;
  int b = blk >> 6;             // 64 l-tiles per batch
  int l0 = (blk & 63) << 5;
  int t = threadIdx.x;
  int ll = t & 31;
  int cg = t >> 5;              // 0..31, each group covers 16 c
  __shared__ float tile[512][33];
  __shared__ float sh_s[32][33];
  __shared__ float sh_q[32][33];
  __shared__ float mu_s[32], rs_s[32];
  const float* xp = x + ((size_t)b * C) * L + l0;
  float s = 0.f, ss = 0.f;
#pragma unroll
  for (int r = 0; r < 16; ++r) {
    int c = cg * 16 + r;
    float v = xp[(size_t)c * L + ll];
    tile[c][ll] = v;
    s += v; ss += v * v;
  }
  sh_s[cg][ll] = s; sh_q[cg][ll] = ss;
  __syncthreads();
  if (t < 32) {
    float ts = 0.f, tq = 0.f;
#pragma unroll
    for (int i = 0; i < 32; ++i) { ts += sh_s[i][t]; tq += sh_q[i][t]; }
    float mu = ts * (1.0f / C);
    float var = tq * (1.0f / C) - mu * mu;
    mu_s[t] = mu;
    rs_s[t] = rsqrtf(var + EPS);
  }
  __syncthreads();
  int c2 = (t & 255) * 2;
  int lgrp = t >> 8;
  float g0 = gamma[c2], g1 = gamma[c2 + 1];
  float b0 = beta[c2],  b1 = beta[c2 + 1];
#pragma unroll
  for (int it = 0; it < 8; ++it) {
    int l = lgrp * 8 + it;
    float mu = mu_s[l], rstd = rs_s[l];
    float v0 = (tile[c2][l]     - mu) * rstd * g0 + b0;
    float v1 = (tile[c2 + 1][l] - mu) * rstd * g1 + b1;
    *(unsigned*)&hn[(size_t)(b * L + l0 + l) * C + c2] = pack_bf16(v0, v1);
  }
  // fused weight conversion: 262144 threads total; wqkv = 3x262144, wproj = 1x262144
  int gid = blk * 1024 + t;
#pragma unroll
  for (int i = 0; i < 3; ++i)
    wqkv_b[gid + i * 262144] = (bf16)wqkv[gid + i * 262144];
  wproj_b[gid] = (bf16)wproj[gid];
}

// ---------------- QKV GEMM: 128x128 tile, global_load_lds, swizzled LDS ----------------
__global__ __launch_bounds__(256) void k_gemm_qkv(const bf16* __restrict__ hn,
                                                  const bf16* __restrict__ wq,
                                                  const float* __restrict__ bq,
                                                  bf16* __restrict__ qg,
                                                  bf16* __restrict__ kg,
                                                  bf16* __restrict__ vg) {
  int mt = blockIdx.x, nt = blockIdx.y;
  int m0 = mt << 7, n0 = nt << 7;
  int t = threadIdx.x, lane = t & 63, w = t >> 6;
  int mw = w >> 1, nw = w & 1;
  int q4 = lane >> 4, c16 = lane & 15;
  __shared__ __align__(16) char smem[36864];
  bf16* As = (bf16*)smem;            // [128][64] 16B-chunk XOR swizzled
  bf16* Bs = (bf16*)(smem + 16384);

  int goff[4], ldsoff[4];
#pragma unroll
  for (int p = 0; p < 4; ++p) {
    int idx = (p * 4 + w) * 64 + lane;
    int row = idx >> 3, s0 = idx & 7;
    goff[p] = row * C + (s0 ^ (row & 7)) * 8;
    ldsoff[p] = (p * 4 + w) * 512;
  }

  f32x4 acc[4][4];
#pragma unroll
  for (int mi = 0; mi < 4; ++mi)
#pragma unroll
    for (int ni = 0; ni < 4; ++ni) acc[mi][ni] = (f32x4){0.f, 0.f, 0.f, 0.f};

  const bf16* ap = hn + (size_t)m0 * C;
  const bf16* bp = wq + (size_t)n0 * C;
  for (int k0 = 0; k0 < C; k0 += 64) {
    __syncthreads();
#pragma unroll
    for (int p = 0; p < 4; ++p) {
      gll16(ap + k0 + goff[p], As + ldsoff[p]);
      gll16(bp + k0 + goff[p], Bs + ldsoff[p]);
    }
    __syncthreads();
#pragma unroll
    for (int kk2 = 0; kk2 < 2; ++kk2) {
      bf16x8 af[4], bfr[4];
#pragma unroll
      for (int mi = 0; mi < 4; ++mi) {
        int row = mw * 64 + mi * 16 + c16;
        af[mi] = ld8(As + row * 64 + ((kk2 * 4 + q4) ^ (row & 7)) * 8);
      }
#pragma unroll
      for (int ni = 0; ni < 4; ++ni) {
        int row = nw * 64 + ni * 16 + c16;
        bfr[ni] = ld8(Bs + row * 64 + ((kk2 * 4 + q4) ^ (row & 7)) * 8);
      }
#pragma unroll
      for (int mi = 0; mi < 4; ++mi)
#pragma unroll
        for (int ni = 0; ni < 4; ++ni)
          acc[mi][ni] = __builtin_amdgcn_mfma_f32_16x16x32_bf16(af[mi], bfr[ni], acc[mi][ni], 0, 0, 0);
    }
  }
  __syncthreads();

  int i = nt >> 2;                    // 0=q 1=k 2=v
  int h = ((nt & 3) << 1) + nw;
  int b = m0 >> 11;
  int l0 = (m0 & (L - 1)) + mw * 64;
  float bias[4];
#pragma unroll
  for (int ni = 0; ni < 4; ++ni) bias[ni] = bq[n0 + nw * 64 + ni * 16 + c16];
  bf16* Os = (bf16*)(smem + w * 9216);  // per-wave [64][72]

  if (i == 2) {
#pragma unroll
    for (int mi = 0; mi < 4; ++mi)
#pragma unroll
      for (int ni = 0; ni < 4; ++ni) {
        bf16x4 pk;
#pragma unroll
        for (int r = 0; r < 4; ++r) pk[r] = (bf16)(acc[mi][ni][r] + bias[ni]);
        *(bf16x4*)&Os[(ni * 16 + c16) * 72 + mi * 16 + q4 * 4] = pk;
      }
    __syncthreads();
    const bf16* src = Os + lane * 72;
    bf16* dst = vg + ((size_t)((b * H + h) * DH + lane)) * L + l0;
#pragma unroll
    for (int s = 0; s < 8; ++s)
      *(uint4*)(dst + s * 8) = *(const uint4*)(src + s * 8);
  } else {
    float sc = (i == 0) ? QSCALE : 1.0f;
#pragma unroll
    for (int mi = 0; mi < 4; ++mi)
#pragma unroll
      for (int ni = 0; ni < 4; ++ni)
#pragma unroll
        for (int r = 0; r < 4; ++r)
          Os[(mi * 16 + q4 * 4 + r) * 72 + ni * 16 + c16] = (bf16)((acc[mi][ni][r] + bias[ni]) * sc);
    __syncthreads();
    bf16* dst0 = (i == 0) ? qg : kg;
    const bf16* src = Os + lane * 72;
    bf16* dst = dst0 + ((size_t)((b * H + h) * L + l0 + lane)) * DH;
#pragma unroll
    for (int s = 0; s < 8; ++s)
      *(uint4*)(dst + s * 8) = *(const uint4*)(src + s * 8);
  }
}

// ---------------- flash attention v13: QBLK=64, 8 blocks/CU (occupancy-driven) ----------------
// Evidence chain: v6 (25.6KB LDS, exposed drain) and v12 (40KB, hidden drain) BOTH ran 54 µs
// at traffic floor (v12 FETCH 15.4 MB, HBM 9%) — grid 1024 = 4 blocks/CU was the binding
// constraint (grid-limited, not resource-limited). Per-wave serial chain ~400+ cy/iter with
// only 4 waves/SIMD -> ~50% issue occupancy, rest is s_waitcnt with no wave ready.
// v13: split q-tiles (NOT j — opart/lsum/proj untouched): 32 bh x 32 qt x 2 js = 2048 blocks
// = 8 blocks/CU = 32 waves/CU. LDS cut to 20480 B (single-buffer K/V 16K + Ps[4][16][32] 4K,
// 3-bit XOR swizzle key (c16&3)<<1, per-kk2 half-rounds) so 8 blocks fit. v6-style
// two-syncthreads loop: exposed stage latency now hidden by 8 waves/SIMD TLP.
// Convoy + XCD swizzle retained (keeps FETCH at floor). VGPR must stay <=64.
__global__ __launch_bounds__(256, 8) void k_attn(const bf16* __restrict__ qg,
                                                 const bf16* __restrict__ kg,
                                                 const bf16* __restrict__ vt,
                                                 bf16* __restrict__ opart,
                                                 float* __restrict__ lsum) {
  // XCD-aware decode: 2048 = 8 XCD x 256 slots; 256 slots cover 4 bh x (2 js x 32 qt),
  // js-major so co-resident blocks stream the same K/V half.
  int i0 = blockIdx.x;
  int x = i0 & 7, slot = i0 >> 3;
  int bh = ((slot >> 6) << 3) + x;   // ∈ [0,32)
  int inner = slot & 63;
  int js = inner >> 5;
  int qt = inner & 31;               // ∈ [0,32), 64 q-rows each
  int t = threadIdx.x, lane = t & 63, w = t >> 6;  // w: 0..3, each wave owns 16 q-rows
  int q4 = lane >> 4, c16 = lane & 15;
  __shared__ __align__(16) bf16 Ks[64][64];     // 16B-chunk XOR swizzled, single buffer
  __shared__ __align__(16) bf16 Vts[64][64];    // [d][j], same swizzle
  __shared__ __align__(16) bf16 Ps[4][16][32];  // per-wave per-kk2 P round-trip, 8B-chunk XOR
  const bf16* qptr  = qg + ((size_t)bh * L + qt * 64 + w * 16) * DH;
  const bf16* kptr  = kg + (size_t)bh * L * DH;
  const bf16* vtptr = vt + (size_t)bh * DH * L;

  int ksoff[2], vsoff[2];
#pragma unroll
  for (int p = 0; p < 2; ++p) {
    int ci = p * 256 + w * 64 + lane;
    int row = ci >> 3, s0 = ci & 7;
    int ch = s0 ^ (row & 7);
    ksoff[p] = row * DH + ch * 8;
    vsoff[p] = row * L + ch * 8;
  }
  int sw = c16 & 7;
  int psw = (c16 & 3) << 1;          // 3-bit even key: b64 writes bijective, b128 reads contiguous

  bf16x8 qf[2];
#pragma unroll
  for (int kk2 = 0; kk2 < 2; ++kk2)
    qf[kk2] = ld8(&qptr[(size_t)c16 * DH + kk2 * 32 + q4 * 8]);

  f32x4 o_acc[4];                    // O^T: col=q(c16), rows d = db*16+q4*4+r
  float l_i = 0.f;
#pragma unroll
  for (int db = 0; db < 4; ++db) o_acc[db] = (f32x4){0.f, 0.f, 0.f, 0.f};

  for (int it = 0; it < 16; ++it) {
    int j0 = js * 1024 + it * 64;
    __syncthreads();                 // previous tile's LDS reads complete before overwrite
#pragma unroll
    for (int p = 0; p < 2; ++p) {
      gll16(kptr + (size_t)j0 * DH + ksoff[p], &Ks[0][0]  + (p * 4 + w) * 512);
      gll16(vtptr + j0 + vsoff[p],             &Vts[0][0] + (p * 4 + w) * 512);
    }
    __syncthreads();                 // compiler emits vmcnt(0) drain -> tile resident

    // S^T[j][q]: A = K (rows=j), B = Q (rows=q); 16 rows of q per wave
    f32x4 s[4];
#pragma unroll
    for (int jb = 0; jb < 4; ++jb) s[jb] = (f32x4){0.f, 0.f, 0.f, 0.f};
#pragma unroll
    for (int kk2 = 0; kk2 < 2; ++kk2) {
      int choff = ((kk2 * 4 + q4) ^ sw) * 8;
#pragma unroll
      for (int jb = 0; jb < 4; ++jb) {
        bf16x8 kf = ld8(&Ks[0][0] + (jb * 16 + c16) * 64 + choff);
        s[jb] = __builtin_amdgcn_mfma_f32_16x16x32_bf16(kf, qf[kk2], s[jb], 0, 0, 0);
      }
    }

    // no-max softmax: P = exp2(S)
    {
      float rs = 0.f;
#pragma unroll
      for (int jb = 0; jb < 4; ++jb)
#pragma unroll
        for (int r = 0; r < 4; ++r) {
          float p_ = __builtin_amdgcn_exp2f(s[jb][r]);
          s[jb][r] = p_;
          rs += p_;
        }
      l_i += rs;
    }

    // O^T += V^T P^T : per-kk2 half-rounds through Ps[w][c16][32]
    // write chunk (jbl*4+q4)^psw holds j = jb*16+q4*4+{0..3}; read base chunk q4*2 yields
    // j = kk2*32+q4*8+{0..7} (B-fragment layout). In-order DS pipe keeps the two rounds safe.
#pragma unroll
    for (int kk2 = 0; kk2 < 2; ++kk2) {
      int choff = ((kk2 * 4 + q4) ^ sw) * 8;
#pragma unroll
      for (int jbl = 0; jbl < 2; ++jbl) {
        int jb = kk2 * 2 + jbl;
        uint2 pk;
        pk.x = pack_bf16(s[jb][0], s[jb][1]);
        pk.y = pack_bf16(s[jb][2], s[jb][3]);
        *(uint2*)&Ps[w][c16][((jbl * 4 + q4) ^ psw) * 4] = pk;
      }
      bf16x8 pf = ld8(&Ps[w][c16][((q4 * 2) ^ psw) * 4]);
#pragma unroll
      for (int db = 0; db < 4; ++db) {
        bf16x8 vfr = ld8(&Vts[0][0] + (db * 16 + c16) * 64 + choff);
        o_acc[db] = __builtin_amdgcn_mfma_f32_16x16x32_bf16(vfr, pf, o_acc[db], 0, 0, 0);
      }
    }
  }

  // epilogue: finish l across quads, store raw partials + l
  {
    float lf = l_i;
    lf += __shfl_xor(lf, 16, 64);
    lf += __shfl_xor(lf, 32, 64);
    int q = qt * 64 + w * 16 + c16;
    bf16* op = opart + (((size_t)js * BH + bh) * L + q) * DH;
#pragma unroll
    for (int db = 0; db < 4; ++db) {
      uint2 pk;
      pk.x = pack_bf16(o_acc[db][0], o_acc[db][1]);
      pk.y = pack_bf16(o_acc[db][2], o_acc[db][3]);
      *(uint2*)&op[db * 16 + q4 * 4] = pk;
    }
    if (q4 == 0) lsum[((size_t)js * BH + bh) * L + q] = lf;
  }
}

// ---------------- proj GEMM with inline split-j merge + bias + residual ----------------
__global__ __launch_bounds__(256) void k_gemm_proj(const bf16* __restrict__ opart,
                                                   const float* __restrict__ lsum,
                                                   const bf16* __restrict__ wp,
                                                   const float* __restrict__ bp,
                                                   const float* __restrict__ x,
                                                   float* __restrict__ out) {
  int mt = blockIdx.x, nt = blockIdx.y;  // 128 x 8
  int m0 = mt << 6, n0 = nt << 6;
  int t = threadIdx.x;
  int lane = t & 63, w = t >> 6;
  int q4 = lane >> 4, c16 = lane & 15;
  __shared__ __align__(16) bf16 As[64][72];
  __shared__ __align__(16) bf16 Bs[64][72];
  __shared__ float Ot[64][65];
  __shared__ float invs[64][9];
  int b = m0 >> 11, q0 = m0 & (L - 1);
  for (int i = t; i < 512; i += 256) {
    int row = i >> 3, h = i & 7;
    int bhh = b * 8 + h;
    float l0v = lsum[(size_t)bhh * L + q0 + row];
    float l1v = lsum[((size_t)BH + bhh) * L + q0 + row];
    invs[row][h] = 1.0f / (l0v + l1v);
  }
  f32x4 acc[4];
#pragma unroll
  for (int nb = 0; nb < 4; ++nb) acc[nb] = (f32x4){0.f, 0.f, 0.f, 0.f};

  for (int k0 = 0; k0 < C; k0 += 64) {
    __syncthreads();
    int h = k0 >> 6;
    const bf16* ap0 = opart + ((size_t)(b * 8 + h) * L + q0) * 64;
    const bf16* ap1 = opart + ((size_t)(BH + b * 8 + h) * L + q0) * 64;
#pragma unroll
    for (int p = 0; p < 2; ++p) {
      int idx = p * 256 + t;
      int row = idx >> 3, ch = idx & 7;
      uint4 u0 = *(const uint4*)(ap0 + (size_t)row * 64 + ch * 8);
      uint4 u1 = *(const uint4*)(ap1 + (size_t)row * 64 + ch * 8);
      float inv = invs[row][h];
      unsigned* pu0 = (unsigned*)&u0;
      unsigned* pu1 = (unsigned*)&u1;
      uint4 m;
      unsigned* pm = (unsigned*)&m;
#pragma unroll
      for (int k = 0; k < 4; ++k)
        pm[k] = pack_bf16((bf_lo(pu0[k]) + bf_lo(pu1[k])) * inv,
                          (bf_hi(pu0[k]) + bf_hi(pu1[k])) * inv);
      *(uint4*)&As[row][ch * 8] = m;
      *(bf16x8*)&Bs[row][ch * 8] = ld8(&wp[(size_t)(n0 + row) * C + k0 + ch * 8]);
    }
    __syncthreads();
#pragma unroll
    for (int kk = 0; kk < 64; kk += 32) {
      bf16x8 a = ld8(&As[w * 16 + c16][kk + q4 * 8]);
#pragma unroll
      for (int nb = 0; nb < 4; ++nb) {
        bf16x8 bfr = ld8(&Bs[nb * 16 + c16][kk + q4 * 8]);
        acc[nb] = __builtin_amdgcn_mfma_f32_16x16x32_bf16(a, bfr, acc[nb], 0, 0, 0);
      }
    }
  }
  __syncthreads();
#pragma unroll
  for (int nb = 0; nb < 4; ++nb)
#pragma unroll
    for (int r = 0; r < 4; ++r)
      Ot[w * 16 + q4 * 4 + r][nb * 16 + c16] = acc[nb][r];
  __syncthreads();
#pragma unroll
  for (int r = 0; r < 16; ++r) {
    int cl = w * 16 + r;
    int c = n0 + cl;
    size_t idx = (size_t)(b * C + c) * L + q0 + lane;
    out[idx] = Ot[lane][cl] + bp[c] + x[idx];
  }
}

extern "C" void kernel_launch(void* const* d_in, const int* in_sizes, int n_in,
                              void* d_out, int out_size, void* d_ws, size_t ws_size,
                              hipStream_t stream) {
  const float* x     = (const float*)d_in[0];
  const float* gamma = (const float*)d_in[1];
  const float* beta  = (const float*)d_in[2];
  const float* wqkv  = (const float*)d_in[3];
  const float* bqkv  = (const float*)d_in[4];
  const float* wproj = (const float*)d_in[5];
  const float* bproj = (const float*)d_in[6];
  float* out = (float*)d_out;
  char* ws = (char*)d_ws;
  bf16* hn  = (bf16*)(ws + OFF_HN);
  bf16* wqb = (bf16*)(ws + OFF_WQKV);
  bf16* wpb = (bf16*)(ws + OFF_WPROJ);
  bf16* qbp = (bf16*)(ws + OFF_Q);
  bf16* kbp = (bf16*)(ws + OFF_K);
  bf16* vbp = (bf16*)(ws + OFF_V);
  bf16* opart = (bf16*)(ws + OFF_OPART);
  float* lsum = (float*)(ws + OFF_ML);

  hipLaunchKernelGGL(k_ln, dim3(B * (L / 32)), dim3(1024), 0, stream,
                     x, gamma, beta, wqkv, wproj, hn, wqb, wpb);
  hipLaunchKernelGGL(k_gemm_qkv, dim3(BL / 128, N_QKV / 128), dim3(256), 0, stream,
                     hn, wqb, bqkv, qbp, kbp, vbp);
  hipLaunchKernelGGL(k_attn, dim3(B * H * (L / 64) * 2), dim3(256), 0, stream,
                     qbp, kbp, vbp, opart, lsum);
  hipLaunchKernelGGL(k_gemm_proj, dim3(BL / 64, C / 64), dim3(256), 0, stream,
                     opart, lsum, wpb, bproj, x, out);
}

// Round 5
// 169.151 us; speedup vs baseline: 1.1103x; 1.1103x over previous
//
#include <hip/hip_runtime.h>
#include <hip/hip_bf16.h>

typedef __bf16 bf16;
typedef bf16 bf16x8 __attribute__((ext_vector_type(8)));
typedef bf16 bf16x4 __attribute__((ext_vector_type(4)));
typedef float f32x4 __attribute__((ext_vector_type(4)));

constexpr int B = 4, C = 512, L = 2048, H = 8, DH = 64;
constexpr int BL = B * L;        // 8192
constexpr int BH = B * H;        // 32
constexpr int N_QKV = 3 * C;     // 1536
constexpr float QSCALE = 0.125f * 1.44269504088896f;  // DH^-0.5 * log2(e), folded into Q
constexpr float EPS = 1e-5f;

// ---- workspace layout (bytes) ----
constexpr size_t SZ = (size_t)BL * C;                 // 4,194,304 elems
constexpr size_t OFF_HN    = 0;                       // SZ bf16
constexpr size_t OFF_WQKV  = OFF_HN    + SZ * 2;      // N_QKV*C bf16
constexpr size_t OFF_WPROJ = OFF_WQKV  + (size_t)N_QKV * C * 2;
constexpr size_t OFF_Q     = OFF_WPROJ + (size_t)C * C * 2;
constexpr size_t OFF_K     = OFF_Q     + SZ * 2;
constexpr size_t OFF_V     = OFF_K     + SZ * 2;      // V stored TRANSPOSED [B,H,DH,L]
constexpr size_t OFF_O     = OFF_V     + SZ * 2;      // (unused)
constexpr size_t OFF_STATS = OFF_O     + SZ * 2;      // (unused)
constexpr size_t OFF_OPART = OFF_STATS + (size_t)BL * 2 * 4;   // [2][BH][L][DH] bf16
constexpr size_t OFF_ML    = OFF_OPART + (size_t)2 * BH * L * DH * 2;  // [2][BH][L] float

__device__ __forceinline__ bf16x8 ld8(const bf16* p) {
  return *(const bf16x8*)p;
}

__device__ __forceinline__ void gll16(const bf16* g, bf16* l) {
  __builtin_amdgcn_global_load_lds(
      (const __attribute__((address_space(1))) unsigned int*)(const void*)g,
      (__attribute__((address_space(3))) unsigned int*)(void*)l, 16, 0, 0);
}

// bias-rounded bf16 pack: (hi16(a+0x8000) low | hi16(b+0x8000) high)
__device__ __forceinline__ unsigned pack_bf16(float a, float b) {
  unsigned ua = __builtin_bit_cast(unsigned, a) + 0x8000u;
  unsigned ub = __builtin_bit_cast(unsigned, b) + 0x8000u;
  return __builtin_amdgcn_perm(ub, ua, 0x07060302u);
}
__device__ __forceinline__ float bf_lo(unsigned u) { return __builtin_bit_cast(float, u << 16); }
__device__ __forceinline__ float bf_hi(unsigned u) { return __builtin_bit_cast(float, u & 0xFFFF0000u); }

// ---------------- fused LayerNorm + weight conversion ----------------
// grid: B * (L/32) = 256 blocks, 1024 threads. x tile (512 c x 32 l fp32) in LDS.
// Tail: converts wqkv (3 strided passes) + wproj (1 pass) to bf16 — replaces k_convert_w.
__global__ __launch_bounds__(1024) void k_ln(const float* __restrict__ x,
                                             const float* __restrict__ gamma,
                                             const float* __restrict__ beta,
                                             const float* __restrict__ wqkv,
                                             const float* __restrict__ wproj,
                                             bf16* __restrict__ hn,
                                             bf16* __restrict__ wqkv_b,
                                             bf16* __restrict__ wproj_b) {
  int blk = blockIdx.x;
  int b = blk >> 6;             // 64 l-tiles per batch
  int l0 = (blk & 63) << 5;
  int t = threadIdx.x;
  int ll = t & 31;
  int cg = t >> 5;              // 0..31, each group covers 16 c
  __shared__ float tile[512][33];
  __shared__ float sh_s[32][33];
  __shared__ float sh_q[32][33];
  __shared__ float mu_s[32], rs_s[32];
  const float* xp = x + ((size_t)b * C) * L + l0;
  float s = 0.f, ss = 0.f;
#pragma unroll
  for (int r = 0; r < 16; ++r) {
    int c = cg * 16 + r;
    float v = xp[(size_t)c * L + ll];
    tile[c][ll] = v;
    s += v; ss += v * v;
  }
  sh_s[cg][ll] = s; sh_q[cg][ll] = ss;
  __syncthreads();
  if (t < 32) {
    float ts = 0.f, tq = 0.f;
#pragma unroll
    for (int i = 0; i < 32; ++i) { ts += sh_s[i][t]; tq += sh_q[i][t]; }
    float mu = ts * (1.0f / C);
    float var = tq * (1.0f / C) - mu * mu;
    mu_s[t] = mu;
    rs_s[t] = rsqrtf(var + EPS);
  }
  __syncthreads();
  int c2 = (t & 255) * 2;
  int lgrp = t >> 8;
  float g0 = gamma[c2], g1 = gamma[c2 + 1];
  float b0 = beta[c2],  b1 = beta[c2 + 1];
#pragma unroll
  for (int it = 0; it < 8; ++it) {
    int l = lgrp * 8 + it;
    float mu = mu_s[l], rstd = rs_s[l];
    float v0 = (tile[c2][l]     - mu) * rstd * g0 + b0;
    float v1 = (tile[c2 + 1][l] - mu) * rstd * g1 + b1;
    *(unsigned*)&hn[(size_t)(b * L + l0 + l) * C + c2] = pack_bf16(v0, v1);
  }
  // fused weight conversion: 262144 threads total; wqkv = 3x262144, wproj = 1x262144
  int gid = blk * 1024 + t;
#pragma unroll
  for (int i = 0; i < 3; ++i)
    wqkv_b[gid + i * 262144] = (bf16)wqkv[gid + i * 262144];
  wproj_b[gid] = (bf16)wproj[gid];
}

// ---------------- QKV GEMM: 128x128 tile, global_load_lds, swizzled LDS ----------------
__global__ __launch_bounds__(256) void k_gemm_qkv(const bf16* __restrict__ hn,
                                                  const bf16* __restrict__ wq,
                                                  const float* __restrict__ bq,
                                                  bf16* __restrict__ qg,
                                                  bf16* __restrict__ kg,
                                                  bf16* __restrict__ vg) {
  int mt = blockIdx.x, nt = blockIdx.y;
  int m0 = mt << 7, n0 = nt << 7;
  int t = threadIdx.x, lane = t & 63, w = t >> 6;
  int mw = w >> 1, nw = w & 1;
  int q4 = lane >> 4, c16 = lane & 15;
  __shared__ __align__(16) char smem[36864];
  bf16* As = (bf16*)smem;            // [128][64] 16B-chunk XOR swizzled
  bf16* Bs = (bf16*)(smem + 16384);

  int goff[4], ldsoff[4];
#pragma unroll
  for (int p = 0; p < 4; ++p) {
    int idx = (p * 4 + w) * 64 + lane;
    int row = idx >> 3, s0 = idx & 7;
    goff[p] = row * C + (s0 ^ (row & 7)) * 8;
    ldsoff[p] = (p * 4 + w) * 512;
  }

  f32x4 acc[4][4];
#pragma unroll
  for (int mi = 0; mi < 4; ++mi)
#pragma unroll
    for (int ni = 0; ni < 4; ++ni) acc[mi][ni] = (f32x4){0.f, 0.f, 0.f, 0.f};

  const bf16* ap = hn + (size_t)m0 * C;
  const bf16* bp = wq + (size_t)n0 * C;
  for (int k0 = 0; k0 < C; k0 += 64) {
    __syncthreads();
#pragma unroll
    for (int p = 0; p < 4; ++p) {
      gll16(ap + k0 + goff[p], As + ldsoff[p]);
      gll16(bp + k0 + goff[p], Bs + ldsoff[p]);
    }
    __syncthreads();
#pragma unroll
    for (int kk2 = 0; kk2 < 2; ++kk2) {
      bf16x8 af[4], bfr[4];
#pragma unroll
      for (int mi = 0; mi < 4; ++mi) {
        int row = mw * 64 + mi * 16 + c16;
        af[mi] = ld8(As + row * 64 + ((kk2 * 4 + q4) ^ (row & 7)) * 8);
      }
#pragma unroll
      for (int ni = 0; ni < 4; ++ni) {
        int row = nw * 64 + ni * 16 + c16;
        bfr[ni] = ld8(Bs + row * 64 + ((kk2 * 4 + q4) ^ (row & 7)) * 8);
      }
#pragma unroll
      for (int mi = 0; mi < 4; ++mi)
#pragma unroll
        for (int ni = 0; ni < 4; ++ni)
          acc[mi][ni] = __builtin_amdgcn_mfma_f32_16x16x32_bf16(af[mi], bfr[ni], acc[mi][ni], 0, 0, 0);
    }
  }
  __syncthreads();

  int i = nt >> 2;                    // 0=q 1=k 2=v
  int h = ((nt & 3) << 1) + nw;
  int b = m0 >> 11;
  int l0 = (m0 & (L - 1)) + mw * 64;
  float bias[4];
#pragma unroll
  for (int ni = 0; ni < 4; ++ni) bias[ni] = bq[n0 + nw * 64 + ni * 16 + c16];
  bf16* Os = (bf16*)(smem + w * 9216);  // per-wave [64][72]

  if (i == 2) {
#pragma unroll
    for (int mi = 0; mi < 4; ++mi)
#pragma unroll
      for (int ni = 0; ni < 4; ++ni) {
        bf16x4 pk;
#pragma unroll
        for (int r = 0; r < 4; ++r) pk[r] = (bf16)(acc[mi][ni][r] + bias[ni]);
        *(bf16x4*)&Os[(ni * 16 + c16) * 72 + mi * 16 + q4 * 4] = pk;
      }
    __syncthreads();
    const bf16* src = Os + lane * 72;
    bf16* dst = vg + ((size_t)((b * H + h) * DH + lane)) * L + l0;
#pragma unroll
    for (int s = 0; s < 8; ++s)
      *(uint4*)(dst + s * 8) = *(const uint4*)(src + s * 8);
  } else {
    float sc = (i == 0) ? QSCALE : 1.0f;
#pragma unroll
    for (int mi = 0; mi < 4; ++mi)
#pragma unroll
      for (int ni = 0; ni < 4; ++ni)
#pragma unroll
        for (int r = 0; r < 4; ++r)
          Os[(mi * 16 + q4 * 4 + r) * 72 + ni * 16 + c16] = (bf16)((acc[mi][ni][r] + bias[ni]) * sc);
    __syncthreads();
    bf16* dst0 = (i == 0) ? qg : kg;
    const bf16* src = Os + lane * 72;
    bf16* dst = dst0 + ((size_t)((b * H + h) * L + l0 + lane)) * DH;
#pragma unroll
    for (int s = 0; s < 8; ++s)
      *(uint4*)(dst + s * 8) = *(const uint4*)(src + s * 8);
  }
}

// ---------------- flash attention v14: v12 skeleton + permlane P-transpose (no Ps LDS) ----------------
// Evidence: v13 (QBLK=64, 8 blk/CU, occ 62%) ran 71 µs — DS-pipe-bound exactly (measured
// wall 10.6K cy/iter ≈ computed DS cost). v12 (54 µs) was ~69% DS-busy; occupancy is NOT
// the lever, DS traffic is. Of v12's 28 DS ops/wave-iter, 12 are the Ps round-trip
// (8 b64 wr + 4 b128 rd) AND it's the longest serial chain (pack->ds_write->lgkm->ds_read).
// v14: replace Ps with an in-register 4x4 u32 quad-group transpose:
//   permlane32_swap(A,C); permlane16_swap(A,C) =>
//   A'' = {A.g0,A.g2,C.g0,C.g2} (=pf0/pf2 halves), per derivation matching v6's verified
//   Ps write [q][jb*16+q4*4+r] / read [q][kk2*32+q4*8] mapping.
// 4 VALU ops replace 12 DS ops per qb-iter; Ps LDS freed (40->32 KB). Everything else = v12
// (QBLK 128, grid 1024, dbuf rotated-drain convoy, XCD swizzle — traffic at floor).
__global__ __launch_bounds__(256, 4) void k_attn(const bf16* __restrict__ qg,
                                                 const bf16* __restrict__ kg,
                                                 const bf16* __restrict__ vt,
                                                 bf16* __restrict__ opart,
                                                 float* __restrict__ lsum) {
  // XCD-aware decode: x = XCD, 128 slots per XCD cover bh ∈ {x, x+8, x+16, x+24};
  // inner js-major: consecutive slots share js (same K/V stream) for convoy sharing.
  int i0 = blockIdx.x;
  int x = i0 & 7, slot = i0 >> 3;
  int bh = ((slot >> 5) << 3) + x;   // (slot/32)*8 + x  ∈ [0,32)
  int inner = slot & 31;
  int js = inner >> 4;
  int qt = inner & 15;
  int t = threadIdx.x, lane = t & 63, w = t >> 6;  // w: 0..3
  int q4 = lane >> 4, c16 = lane & 15;
  __shared__ __align__(16) bf16 Ks[2][64][64];    // 16B-chunk XOR swizzled, double-buffered
  __shared__ __align__(16) bf16 Vts[2][64][64];   // [d][j], same swizzle, double-buffered
  const bf16* qptr  = qg + ((size_t)bh * L + qt * 128 + w * 32) * DH;
  const bf16* kptr  = kg + (size_t)bh * L * DH;
  const bf16* vtptr = vt + (size_t)bh * DH * L;

  int ksoff[2], vsoff[2];
#pragma unroll
  for (int p = 0; p < 2; ++p) {
    int ci = p * 256 + w * 64 + lane;
    int row = ci >> 3, s0 = ci & 7;
    int ch = s0 ^ (row & 7);
    ksoff[p] = row * DH + ch * 8;
    vsoff[p] = row * L + ch * 8;
  }
  int sw = c16 & 7;

  bf16x8 qf[2][2];
#pragma unroll
  for (int qb = 0; qb < 2; ++qb)
#pragma unroll
    for (int kk2 = 0; kk2 < 2; ++kk2)
      qf[qb][kk2] = ld8(&qptr[(size_t)(qb * 16 + c16) * DH + kk2 * 32 + q4 * 8]);

  f32x4 o_acc[2][4];                 // O^T: col=q(c16), rows d = db*16+q4*4+r
  float l_i[2] = {0.f, 0.f};
#pragma unroll
  for (int qb = 0; qb < 2; ++qb)
#pragma unroll
    for (int db = 0; db < 4; ++db) o_acc[qb][db] = (f32x4){0.f, 0.f, 0.f, 0.f};

  // prologue: stage j-tile 0 into buffer 0, full drain + barrier (iter 0 reads it)
  {
    int j0 = js * 1024;
#pragma unroll
    for (int p = 0; p < 2; ++p) {
      gll16(kptr + (size_t)j0 * DH + ksoff[p], &Ks[0][0][0]  + (p * 4 + w) * 512);
      gll16(vtptr + j0 + vsoff[p],             &Vts[0][0][0] + (p * 4 + w) * 512);
    }
  }
  asm volatile("s_waitcnt vmcnt(0)" ::: "memory");
  __builtin_amdgcn_s_barrier();
  __builtin_amdgcn_sched_barrier(0);

  for (int it = 0; it < 16; ++it) {
    int cur = it & 1;
    // issue next-tile stage FIRST: these loads fly across the whole compute phase
    if (it < 15) {
      int j1 = js * 1024 + (it + 1) * 64;
#pragma unroll
      for (int p = 0; p < 2; ++p) {
        gll16(kptr + (size_t)j1 * DH + ksoff[p], &Ks[cur ^ 1][0][0]  + (p * 4 + w) * 512);
        gll16(vtptr + j1 + vsoff[p],             &Vts[cur ^ 1][0][0] + (p * 4 + w) * 512);
      }
    }
    const bf16* KsC = &Ks[cur][0][0];
    const bf16* VsC = &Vts[cur][0][0];

    // S^T[j][q]: A = K (rows=j), B = Q (rows=q)
    f32x4 s[2][4];
#pragma unroll
    for (int qb = 0; qb < 2; ++qb)
#pragma unroll
      for (int jb = 0; jb < 4; ++jb) s[qb][jb] = (f32x4){0.f, 0.f, 0.f, 0.f};
#pragma unroll
    for (int kk2 = 0; kk2 < 2; ++kk2) {
      int choff = ((kk2 * 4 + q4) ^ sw) * 8;
#pragma unroll
      for (int jb = 0; jb < 4; ++jb) {
        bf16x8 kf = ld8(KsC + (jb * 16 + c16) * 64 + choff);
        s[0][jb] = __builtin_amdgcn_mfma_f32_16x16x32_bf16(kf, qf[0][kk2], s[0][jb], 0, 0, 0);
        s[1][jb] = __builtin_amdgcn_mfma_f32_16x16x32_bf16(kf, qf[1][kk2], s[1][jb], 0, 0, 0);
      }
    }

    // no-max softmax: P = exp2(S)
#pragma unroll
    for (int qb = 0; qb < 2; ++qb) {
      float rs = 0.f;
#pragma unroll
      for (int jb = 0; jb < 4; ++jb)
#pragma unroll
        for (int r = 0; r < 4; ++r) {
          float p_ = __builtin_amdgcn_exp2f(s[qb][jb][r]);
          s[qb][jb][r] = p_;
          rs += p_;
        }
      l_i[qb] += rs;
    }

    // V^T A-fragments (shared across both qb)
    bf16x8 vf[2][4];
#pragma unroll
    for (int kk2 = 0; kk2 < 2; ++kk2) {
      int choff = ((kk2 * 4 + q4) ^ sw) * 8;
#pragma unroll
      for (int db = 0; db < 4; ++db)
        vf[kk2][db] = ld8(VsC + (db * 16 + c16) * 64 + choff);
    }

    // O^T += V^T P^T : P B-fragment via in-register quad-group transpose (VALU, no LDS).
    // Target (matches v6's verified Ps read): lane(c16,q4) needs P[q=c16][j=kk2*32+q4*8+0..7].
    // Sources: pk pairs of s[jb] live at lane group sq4 with j=jb*16+sq4*4+{0..3}.
#pragma unroll
    for (int qb = 0; qb < 2; ++qb) {
#pragma unroll
      for (int kk2 = 0; kk2 < 2; ++kk2) {
        unsigned a = pack_bf16(s[qb][2 * kk2][0],     s[qb][2 * kk2][1]);
        unsigned b = pack_bf16(s[qb][2 * kk2][2],     s[qb][2 * kk2][3]);
        unsigned c = pack_bf16(s[qb][2 * kk2 + 1][0], s[qb][2 * kk2 + 1][1]);
        unsigned d = pack_bf16(s[qb][2 * kk2 + 1][2], s[qb][2 * kk2 + 1][3]);
        // A'={A.g01,C.g01}, C'={A.g23,C.g23}; then A''={A.g0,A.g2,C.g0,C.g2}, C''={A.g1,A.g3,C.g1,C.g3}
        asm("v_permlane32_swap_b32 %0, %1" : "+v"(a), "+v"(c));
        asm("v_permlane32_swap_b32 %0, %1" : "+v"(b), "+v"(d));
        asm("v_permlane16_swap_b32 %0, %1" : "+v"(a), "+v"(c));
        asm("v_permlane16_swap_b32 %0, %1" : "+v"(b), "+v"(d));
        uint4 pu = {a, b, c, d};     // pf u32s: j {+0,+1},{+2,+3},{+4,+5},{+6,+7}
        bf16x8 pf = __builtin_bit_cast(bf16x8, pu);
#pragma unroll
        for (int db = 0; db < 4; ++db)
          o_acc[qb][db] = __builtin_amdgcn_mfma_f32_16x16x32_bf16(vf[kk2][db], pf, o_acc[qb][db], 0, 0, 0);
      }
    }

    // full drain at iter END: prefetch had the whole compute phase to land ->
    // wait ~free when L2-resident; global re-sync every iter -> convoy preserved.
    asm volatile("s_waitcnt vmcnt(0)" ::: "memory");
    __builtin_amdgcn_s_barrier();
    __builtin_amdgcn_sched_barrier(0);
  }

  // epilogue: finish l across quads, store raw partials + l
#pragma unroll
  for (int qb = 0; qb < 2; ++qb) {
    float lf = l_i[qb];
    lf += __shfl_xor(lf, 16, 64);
    lf += __shfl_xor(lf, 32, 64);
    int q = qt * 128 + w * 32 + qb * 16 + c16;
    bf16* op = opart + (((size_t)js * BH + bh) * L + q) * DH;
#pragma unroll
    for (int db = 0; db < 4; ++db) {
      uint2 pk;
      pk.x = pack_bf16(o_acc[qb][db][0], o_acc[qb][db][1]);
      pk.y = pack_bf16(o_acc[qb][db][2], o_acc[qb][db][3]);
      *(uint2*)&op[db * 16 + q4 * 4] = pk;
    }
    if (q4 == 0) lsum[((size_t)js * BH + bh) * L + q] = lf;
  }
}

// ---------------- proj GEMM with inline split-j merge + bias + residual ----------------
__global__ __launch_bounds__(256) void k_gemm_proj(const bf16* __restrict__ opart,
                                                   const float* __restrict__ lsum,
                                                   const bf16* __restrict__ wp,
                                                   const float* __restrict__ bp,
                                                   const float* __restrict__ x,
                                                   float* __restrict__ out) {
  int mt = blockIdx.x, nt = blockIdx.y;  // 128 x 8
  int m0 = mt << 6, n0 = nt << 6;
  int t = threadIdx.x;
  int lane = t & 63, w = t >> 6;
  int q4 = lane >> 4, c16 = lane & 15;
  __shared__ __align__(16) bf16 As[64][72];
  __shared__ __align__(16) bf16 Bs[64][72];
  __shared__ float Ot[64][65];
  __shared__ float invs[64][9];
  int b = m0 >> 11, q0 = m0 & (L - 1);
  for (int i = t; i < 512; i += 256) {
    int row = i >> 3, h = i & 7;
    int bhh = b * 8 + h;
    float l0v = lsum[(size_t)bhh * L + q0 + row];
    float l1v = lsum[((size_t)BH + bhh) * L + q0 + row];
    invs[row][h] = 1.0f / (l0v + l1v);
  }
  f32x4 acc[4];
#pragma unroll
  for (int nb = 0; nb < 4; ++nb) acc[nb] = (f32x4){0.f, 0.f, 0.f, 0.f};

  for (int k0 = 0; k0 < C; k0 += 64) {
    __syncthreads();
    int h = k0 >> 6;
    const bf16* ap0 = opart + ((size_t)(b * 8 + h) * L + q0) * 64;
    const bf16* ap1 = opart + ((size_t)(BH + b * 8 + h) * L + q0) * 64;
#pragma unroll
    for (int p = 0; p < 2; ++p) {
      int idx = p * 256 + t;
      int row = idx >> 3, ch = idx & 7;
      uint4 u0 = *(const uint4*)(ap0 + (size_t)row * 64 + ch * 8);
      uint4 u1 = *(const uint4*)(ap1 + (size_t)row * 64 + ch * 8);
      float inv = invs[row][h];
      unsigned* pu0 = (unsigned*)&u0;
      unsigned* pu1 = (unsigned*)&u1;
      uint4 m;
      unsigned* pm = (unsigned*)&m;
#pragma unroll
      for (int k = 0; k < 4; ++k)
        pm[k] = pack_bf16((bf_lo(pu0[k]) + bf_lo(pu1[k])) * inv,
                          (bf_hi(pu0[k]) + bf_hi(pu1[k])) * inv);
      *(uint4*)&As[row][ch * 8] = m;
      *(bf16x8*)&Bs[row][ch * 8] = ld8(&wp[(size_t)(n0 + row) * C + k0 + ch * 8]);
    }
    __syncthreads();
#pragma unroll
    for (int kk = 0; kk < 64; kk += 32) {
      bf16x8 a = ld8(&As[w * 16 + c16][kk + q4 * 8]);
#pragma unroll
      for (int nb = 0; nb < 4; ++nb) {
        bf16x8 bfr = ld8(&Bs[nb * 16 + c16][kk + q4 * 8]);
        acc[nb] = __builtin_amdgcn_mfma_f32_16x16x32_bf16(a, bfr, acc[nb], 0, 0, 0);
      }
    }
  }
  __syncthreads();
#pragma unroll
  for (int nb = 0; nb < 4; ++nb)
#pragma unroll
    for (int r = 0; r < 4; ++r)
      Ot[w * 16 + q4 * 4 + r][nb * 16 + c16] = acc[nb][r];
  __syncthreads();
#pragma unroll
  for (int r = 0; r < 16; ++r) {
    int cl = w * 16 + r;
    int c = n0 + cl;
    size_t idx = (size_t)(b * C + c) * L + q0 + lane;
    out[idx] = Ot[lane][cl] + bp[c] + x[idx];
  }
}

extern "C" void kernel_launch(void* const* d_in, const int* in_sizes, int n_in,
                              void* d_out, int out_size, void* d_ws, size_t ws_size,
                              hipStream_t stream) {
  const float* x     = (const float*)d_in[0];
  const float* gamma = (const float*)d_in[1];
  const float* beta  = (const float*)d_in[2];
  const float* wqkv  = (const float*)d_in[3];
  const float* bqkv  = (const float*)d_in[4];
  const float* wproj = (const float*)d_in[5];
  const float* bproj = (const float*)d_in[6];
  float* out = (float*)d_out;
  char* ws = (char*)d_ws;
  bf16* hn  = (bf16*)(ws + OFF_HN);
  bf16* wqb = (bf16*)(ws + OFF_WQKV);
  bf16* wpb = (bf16*)(ws + OFF_WPROJ);
  bf16* qbp = (bf16*)(ws + OFF_Q);
  bf16* kbp = (bf16*)(ws + OFF_K);
  bf16* vbp = (bf16*)(ws + OFF_V);
  bf16* opart = (bf16*)(ws + OFF_OPART);
  float* lsum = (float*)(ws + OFF_ML);

  hipLaunchKernelGGL(k_ln, dim3(B * (L / 32)), dim3(1024), 0, stream,
                     x, gamma, beta, wqkv, wproj, hn, wqb, wpb);
  hipLaunchKernelGGL(k_gemm_qkv, dim3(BL / 128, N_QKV / 128), dim3(256), 0, stream,
                     hn, wqb, bqkv, qbp, kbp, vbp);
  hipLaunchKernelGGL(k_attn, dim3(B * H * (L / 128) * 2), dim3(256), 0, stream,
                     qbp, kbp, vbp, opart, lsum);
  hipLaunchKernelGGL(k_gemm_proj, dim3(BL / 64, C / 64), dim3(256), 0, stream,
                     opart, lsum, wpb, bproj, x, out);
}